// Round 3
// baseline (499.481 us; speedup 1.0000x reference)
//
#include <hip/hip_runtime.h>
#include <hip/hip_bf16.h>

#define NB 8
#define NC 192
#define NH 4
#define CH 48
#define C3 576
#define HW 16384
#define IW 128

typedef __attribute__((ext_vector_type(4))) float f32x4;
typedef __attribute__((ext_vector_type(8))) short short8;

__device__ __forceinline__ unsigned short f2bf(float f) {
    union { float f; unsigned u; } v; v.f = f;
    unsigned u = v.u;
    return (unsigned short)((u + 0x7FFFu + ((u >> 16) & 1u)) >> 16);
}
__device__ __forceinline__ float bf2f(unsigned short h) {
    union { unsigned u; float f; } v; v.u = ((unsigned)h) << 16;
    return v.f;
}

// ---------------- K0: convert x (fp32 NCHW) -> X4 bf16 quad-interleaved [b][k/4][n][k%4]
__global__ __launch_bounds__(256) void k0_cvt(const float* __restrict__ x,
                                              ushort* __restrict__ X4) {
    unsigned i = blockIdx.x * 256u + threadIdx.x;   // quad id: (b*48+kq)*HW + n
    unsigned n = i & (HW - 1);
    unsigned bk = i >> 14;
    const float* xp = x + (size_t)bk * 4 * HW + n;
    ushort4 v;
    v.x = f2bf(xp[0]);
    v.y = f2bf(xp[HW]);
    v.z = f2bf(xp[2 * HW]);
    v.w = f2bf(xp[3 * HW]);
    *reinterpret_cast<ushort4*>(X4 + (size_t)i * 4) = v;
}

// ---------------- K1: qkv 1x1 conv as bf16 MFMA GEMM, coalesced epilogue via LDS
// grid: mt FASTEST so the 9 m-tiles sharing an X-panel are dispatched adjacently.
__global__ __launch_bounds__(256) void k1_qkv(const float* __restrict__ Wq,
                                              const float* __restrict__ bq,
                                              const uint2* __restrict__ X4,
                                              ushort* __restrict__ qkv) {
    __shared__ __align__(16) ushort xfer[64 * 264];   // stride 264: 16B-aligned rows, ~2-way banks
    int bid = blockIdx.x;
    int mt = bid % 9;
    int rem = bid / 9;
    int chunk = rem & 15;
    int b = rem >> 4;
    int t = threadIdx.x;
    int lane = t & 63, w = t >> 6;
    int g = lane >> 4, r = lane & 15;
    int mw = w & 1, nw = w >> 1;
    int mbase = mt * 64 + mw * 32;

    short8 a[2][6];
#pragma unroll
    for (int mf = 0; mf < 2; ++mf)
#pragma unroll
        for (int ks = 0; ks < 6; ++ks) {
            const float* wp = Wq + (mbase + mf * 16 + r) * NC + ks * 32 + 8 * g;
            short8 av;
#pragma unroll
            for (int j = 0; j < 8; ++j) av[j] = (short)f2bf(wp[j]);
            a[mf][ks] = av;
        }
    float bias[2][4];
#pragma unroll
    for (int mf = 0; mf < 2; ++mf)
#pragma unroll
        for (int rg = 0; rg < 4; ++rg)
            bias[mf][rg] = bq[mbase + mf * 16 + 4 * g + rg];

    const uint2* Xb = X4 + (size_t)b * 48 * HW;
    ushort* outb = qkv + (size_t)b * C3 * HW;

    for (int u = 0; u < 4; ++u) {
        int n0 = chunk * 1024 + u * 256 + nw * 128;
        f32x4 acc[2][8];
#pragma unroll
        for (int mf = 0; mf < 2; ++mf)
#pragma unroll
            for (int nf = 0; nf < 8; ++nf) acc[mf][nf] = (f32x4){0.f, 0.f, 0.f, 0.f};
#pragma unroll
        for (int ks = 0; ks < 6; ++ks) {
            short8 bb[8];
#pragma unroll
            for (int nf = 0; nf < 8; ++nf) {
                int n = n0 + nf * 16 + r;
                int kq = 8 * ks + 2 * g;
                union { uint2 u2[2]; short8 s; } uu;
                uu.u2[0] = Xb[(size_t)kq * HW + n];
                uu.u2[1] = Xb[(size_t)(kq + 1) * HW + n];
                bb[nf] = uu.s;
            }
#pragma unroll
            for (int mf = 0; mf < 2; ++mf)
#pragma unroll
                for (int nf = 0; nf < 8; ++nf)
                    acc[mf][nf] = __builtin_amdgcn_mfma_f32_16x16x32_bf16(
                        a[mf][ks], bb[nf], acc[mf][nf], 0, 0, 0);
        }
        // epilogue: fragments -> LDS tile -> coalesced short8 stores
#pragma unroll
        for (int mf = 0; mf < 2; ++mf)
#pragma unroll
            for (int nf = 0; nf < 8; ++nf) {
                int lcol = nw * 128 + nf * 16 + r;
#pragma unroll
                for (int rg = 0; rg < 4; ++rg) {
                    int lrow = mw * 32 + mf * 16 + 4 * g + rg;
                    xfer[lrow * 264 + lcol] = f2bf(acc[mf][nf][rg] + bias[mf][rg]);
                }
            }
        __syncthreads();
        int n0b = chunk * 1024 + u * 256;
#pragma unroll
        for (int i = 0; i < 8; ++i) {
            int row = (t >> 5) + 8 * i;
            int seg = t & 31;
            short8 v = *reinterpret_cast<const short8*>(&xfer[row * 264 + seg * 8]);
            *reinterpret_cast<short8*>(&outb[(size_t)(mt * 64 + row) * HW + n0b + seg * 8]) = v;
        }
        __syncthreads();
    }
}

// ---------------- K2a: streaming depthwise 3x3 over 4 channels x (128x16) strip.
// mode 0: write plain [b][ch][n] bf16 to dst (batch stride dbs)
// mode 1: scale by (1+mask*tb), write quad-interleaved [b][ch/4][n][ch%4]
__global__ __launch_bounds__(256) void k2a_dw(const ushort* __restrict__ src,
                                              size_t sbs,
                                              ushort* __restrict__ dst,
                                              size_t dbs,
                                              const float* __restrict__ dw_w,
                                              const float* __restrict__ dw_b,
                                              int wb_off,
                                              const float* __restrict__ mask,
                                              const float* __restrict__ tboost,
                                              int mode) {
    __shared__ ushort stage[4][18][128];
    int bid = blockIdx.x;
    int b = bid / 384;
    int rem = bid - b * 384;
    int grp = rem >> 3;         // 0..47 (4-channel group)
    int strip = rem & 7;        // 0..7 (16-row strip)
    int t = threadIdx.x;
    int y = t >> 4;             // 0..15
    int x0 = (t & 15) * 8;

    // stage: 4 ch x 18 rows x 16 short8-segments, coalesced
    for (int u = t; u < 1152; u += 256) {
        int ci = u / 288;
        int r2 = u - ci * 288;
        int row = r2 >> 4;
        int seg = r2 & 15;
        int gy = strip * 16 - 1 + row;
        short8 v = (short8){0, 0, 0, 0, 0, 0, 0, 0};
        if ((unsigned)gy < 128u)
            v = *reinterpret_cast<const short8*>(
                src + (size_t)b * sbs + (size_t)(grp * 4 + ci) * HW + gy * IW + seg * 8);
        *reinterpret_cast<short8*>(&stage[ci][row][seg * 8]) = v;
    }
    __syncthreads();

    float o4[4][8];
#pragma unroll
    for (int ci = 0; ci < 4; ++ci) {
        int gch = wb_off + grp * 4 + ci;
        const float* wt = dw_w + gch * 9;
        float w0 = wt[0], w1 = wt[1], w2 = wt[2];
        float w3 = wt[3], w4 = wt[4], w5 = wt[5];
        float w6 = wt[6], w7 = wt[7], w8 = wt[8];
        float bsv = dw_b[gch];
        float o[8];
#pragma unroll
        for (int p = 0; p < 8; ++p) o[p] = bsv;
#pragma unroll
        for (int dy = 0; dy < 3; ++dy) {
            int row = y + dy;
            short8 m = *reinterpret_cast<const short8*>(&stage[ci][row][x0]);
            float v[10];
            v[0] = (x0 > 0) ? bf2f(stage[ci][row][x0 - 1]) : 0.f;
            v[9] = (x0 < 120) ? bf2f(stage[ci][row][x0 + 8]) : 0.f;
#pragma unroll
            for (int j = 0; j < 8; ++j) v[j + 1] = bf2f((unsigned short)m[j]);
            float wa = (dy == 0) ? w0 : (dy == 1) ? w3 : w6;
            float wb = (dy == 0) ? w1 : (dy == 1) ? w4 : w7;
            float wc = (dy == 0) ? w2 : (dy == 1) ? w5 : w8;
#pragma unroll
            for (int p = 0; p < 8; ++p)
                o[p] += v[p] * wa + v[p + 1] * wb + v[p + 2] * wc;
        }
#pragma unroll
        for (int p = 0; p < 8; ++p) o4[ci][p] = o[p];
    }

    int n = (strip * 16 + y) * IW + x0;
    if (mode == 0) {
#pragma unroll
        for (int ci = 0; ci < 4; ++ci) {
            short8 pk;
#pragma unroll
            for (int p = 0; p < 8; ++p) pk[p] = (short)f2bf(o4[ci][p]);
            *reinterpret_cast<short8*>(
                dst + (size_t)b * dbs + (size_t)(grp * 4 + ci) * HW + n) = pk;
        }
    } else {
        float tb = tboost[0];
        tb = fminf(fmaxf(tb, 0.1f), 0.5f);
        const float* mp = mask + (size_t)b * HW + n;
        float vs[8];
#pragma unroll
        for (int p = 0; p < 8; ++p) vs[p] = 1.f + mp[p] * tb;
        ushort* dp = dst + (size_t)b * dbs + ((size_t)grp * HW + n) * 4;
#pragma unroll
        for (int p = 0; p < 8; p += 2) {
            uint4 W;
            unsigned a0 = f2bf(o4[0][p] * vs[p]), a1 = f2bf(o4[1][p] * vs[p]);
            unsigned a2 = f2bf(o4[2][p] * vs[p]), a3 = f2bf(o4[3][p] * vs[p]);
            unsigned b0 = f2bf(o4[0][p + 1] * vs[p + 1]), b1 = f2bf(o4[1][p + 1] * vs[p + 1]);
            unsigned b2 = f2bf(o4[2][p + 1] * vs[p + 1]), b3 = f2bf(o4[3][p + 1] * vs[p + 1]);
            W.x = a0 | (a1 << 16);
            W.y = a2 | (a3 << 16);
            W.z = b0 | (b1 << 16);
            W.w = b2 | (b3 << 16);
            *reinterpret_cast<uint4*>(dp + p * 4) = W;
        }
    }
}

// ---------------- K2b: Gram + sumsq via MFMA. grid = b(8)*h(4)*chunk(16), chunk=1024 n.
__global__ __launch_bounds__(256) void k2b_gram(const ushort* __restrict__ Qp,
                                                const ushort* __restrict__ Kp,
                                                size_t kbs,
                                                float* __restrict__ gram,
                                                float* __restrict__ ssq,
                                                float* __restrict__ ssk) {
    int bid = blockIdx.x;
    int chunk = bid & 15;
    int h = (bid >> 4) & 3;
    int b = bid >> 6;
    int t = threadIdx.x;
    int lane = t & 63, wv = t >> 6;
    int g = lane >> 4, r = lane & 15;

    const ushort* qb = Qp + (size_t)b * NC * HW + (size_t)(h * CH) * HW;
    const ushort* kb = Kp + (size_t)b * kbs + (size_t)(h * CH) * HW;

    f32x4 gacc[3][3], gqq[3], gkk[3];
#pragma unroll
    for (int i = 0; i < 3; ++i) {
        gqq[i] = (f32x4){0.f, 0.f, 0.f, 0.f};
        gkk[i] = (f32x4){0.f, 0.f, 0.f, 0.f};
#pragma unroll
        for (int j = 0; j < 3; ++j) gacc[i][j] = (f32x4){0.f, 0.f, 0.f, 0.f};
    }

    int nbase = chunk * 1024 + wv * 256;
#pragma unroll 2
    for (int ks = 0; ks < 8; ++ks) {
        int p0 = nbase + ks * 32 + 8 * g;
        short8 qa[3], ka[3];
#pragma unroll
        for (int f = 0; f < 3; ++f) {
            qa[f] = *reinterpret_cast<const short8*>(qb + (size_t)(f * 16 + r) * HW + p0);
            ka[f] = *reinterpret_cast<const short8*>(kb + (size_t)(f * 16 + r) * HW + p0);
        }
#pragma unroll
        for (int cf = 0; cf < 3; ++cf)
#pragma unroll
            for (int df = 0; df < 3; ++df)
                gacc[cf][df] = __builtin_amdgcn_mfma_f32_16x16x32_bf16(
                    qa[cf], ka[df], gacc[cf][df], 0, 0, 0);
#pragma unroll
        for (int f = 0; f < 3; ++f) {
            gqq[f] = __builtin_amdgcn_mfma_f32_16x16x32_bf16(qa[f], qa[f], gqq[f], 0, 0, 0);
            gkk[f] = __builtin_amdgcn_mfma_f32_16x16x32_bf16(ka[f], ka[f], gkk[f], 0, 0, 0);
        }
    }

    float* gr = gram + (size_t)(b * NH + h) * 2304;
#pragma unroll
    for (int cf = 0; cf < 3; ++cf)
#pragma unroll
        for (int df = 0; df < 3; ++df)
#pragma unroll
            for (int rg = 0; rg < 4; ++rg)
                atomicAdd(gr + (cf * 16 + 4 * g + rg) * 48 + df * 16 + r,
                          gacc[cf][df][rg]);
    // diagonal of qq/kk blocks: D[row=4g+rg][col=r]; diag where r==4g+rg
    if ((r >> 2) == g) {
        int rg = r & 3;
#pragma unroll
        for (int f = 0; f < 3; ++f) {
            atomicAdd(ssq + (b * NH + h) * CH + f * 16 + r, gqq[f][rg]);
            atomicAdd(ssk + (b * NH + h) * CH + f * 16 + r, gkk[f][rg]);
        }
    }
}

// ---------------- K4: texture mean + normalize Gram + softmax + W2 = out_w * blockdiag(attn)
__global__ __launch_bounds__(256) void k4_w2(const float* __restrict__ gram,
                                             const float* __restrict__ ssq,
                                             const float* __restrict__ ssk,
                                             const float* __restrict__ mask,
                                             const float* __restrict__ dtemp,
                                             const float* __restrict__ stemp,
                                             const float* __restrict__ out_w,
                                             float* __restrict__ W2) {
    __shared__ float att[48][48];
    __shared__ float invk_s[48];
    __shared__ float red[4];
    __shared__ float tl_s;
    int bid = blockIdx.x;
    int h = bid & 3, b = bid >> 2;
    int t = threadIdx.x;
    // texture level = mean(mask[b]) (redundant across the 4 h-blocks; tiny, L2-hot)
    {
        float s = 0.f;
        const float* mp = mask + (size_t)b * HW;
        for (int i = t; i < HW; i += 256) s += mp[i];
#pragma unroll
        for (int off = 32; off > 0; off >>= 1) s += __shfl_xor(s, off);
        if ((t & 63) == 0) red[t >> 6] = s;
        __syncthreads();
        if (t == 0) tl_s = (red[0] + red[1] + red[2] + red[3]) * (1.f / HW);
        __syncthreads();
    }
    float tl = tl_s;
    float temp = dtemp[h] * tl + stemp[h] * (1.f - tl);
    const float* G = gram + (size_t)(b * NH + h) * 2304;
    const float* sq = ssq + (b * NH + h) * CH;
    const float* sk = ssk + (b * NH + h) * CH;
    if (t < 48) invk_s[t] = 1.f / fmaxf(sqrtf(sk[t]), 1e-12f);
    __syncthreads();
    if (t < 48) {
        float invq = temp / fmaxf(sqrtf(sq[t]), 1e-12f);
        float mx = -1e30f;
        for (int d = 0; d < 48; ++d) {
            float v = G[t * 48 + d] * invq * invk_s[d];
            att[t][d] = v;
            mx = fmaxf(mx, v);
        }
        float sum = 0.f;
        for (int d = 0; d < 48; ++d) {
            float e = __expf(att[t][d] - mx);
            att[t][d] = e;
            sum += e;
        }
        float inv = 1.f / sum;
        for (int d = 0; d < 48; ++d) att[t][d] *= inv;
    }
    __syncthreads();
    for (int i = t; i < NC * 48; i += 256) {
        int oc = i / 48, d = i - oc * 48;
        float s = 0.f;
        for (int c = 0; c < 48; ++c) s += out_w[oc * NC + h * CH + c] * att[c][d];
        W2[(size_t)(b * NC + oc) * NC + h * CH + d] = s;
    }
}

// ---------------- K5: out[b][m][n] = sum_j W2[b][m][j] * v_scaled[b][j][n] + out_b[m]
__global__ __launch_bounds__(256) void k5_out(const float* __restrict__ W2,
                                              const float* __restrict__ ob,
                                              const ushort* __restrict__ Vt4base,
                                              size_t vbs,
                                              float* __restrict__ out) {
    __shared__ __align__(16) float xferf[64 * 260];   // stride 260 f32: 16B-aligned, 2-way banks
    int bid = blockIdx.x;
    int mt = bid % 3;
    int rem = bid / 3;
    int chunk = rem & 31;
    int b = rem >> 5;
    int t = threadIdx.x;
    int lane = t & 63, w = t >> 6;
    int g = lane >> 4, r = lane & 15;
    int mw = w & 1, nw = w >> 1;
    int mbase = mt * 64 + mw * 32;
    const float* Wb = W2 + (size_t)b * NC * NC;

    short8 a[2][6];
#pragma unroll
    for (int mf = 0; mf < 2; ++mf)
#pragma unroll
        for (int ks = 0; ks < 6; ++ks) {
            const float* wp = Wb + (mbase + mf * 16 + r) * NC + ks * 32 + 8 * g;
            short8 av;
#pragma unroll
            for (int j = 0; j < 8; ++j) av[j] = (short)f2bf(wp[j]);
            a[mf][ks] = av;
        }
    float bias[2][4];
#pragma unroll
    for (int mf = 0; mf < 2; ++mf)
#pragma unroll
        for (int rg = 0; rg < 4; ++rg)
            bias[mf][rg] = ob[mbase + mf * 16 + 4 * g + rg];

    const uint2* Vb = reinterpret_cast<const uint2*>(Vt4base + (size_t)b * vbs);
    float* outp = out + (size_t)b * NC * HW;

    for (int u = 0; u < 2; ++u) {
        int n0 = chunk * 512 + u * 256 + nw * 128;
        f32x4 acc[2][8];
#pragma unroll
        for (int mf = 0; mf < 2; ++mf)
#pragma unroll
            for (int nf = 0; nf < 8; ++nf) acc[mf][nf] = (f32x4){0.f, 0.f, 0.f, 0.f};
#pragma unroll
        for (int ks = 0; ks < 6; ++ks) {
            short8 bb[8];
#pragma unroll
            for (int nf = 0; nf < 8; ++nf) {
                int n = n0 + nf * 16 + r;
                int kq = 8 * ks + 2 * g;
                union { uint2 u2[2]; short8 s; } uu;
                uu.u2[0] = Vb[(size_t)kq * HW + n];
                uu.u2[1] = Vb[(size_t)(kq + 1) * HW + n];
                bb[nf] = uu.s;
            }
#pragma unroll
            for (int mf = 0; mf < 2; ++mf)
#pragma unroll
                for (int nf = 0; nf < 8; ++nf)
                    acc[mf][nf] = __builtin_amdgcn_mfma_f32_16x16x32_bf16(
                        a[mf][ks], bb[nf], acc[mf][nf], 0, 0, 0);
        }
        // epilogue: fragments -> LDS -> coalesced float4 stores
#pragma unroll
        for (int mf = 0; mf < 2; ++mf)
#pragma unroll
            for (int nf = 0; nf < 8; ++nf) {
                int lcol = nw * 128 + nf * 16 + r;
#pragma unroll
                for (int rg = 0; rg < 4; ++rg) {
                    int lrow = mw * 32 + mf * 16 + 4 * g + rg;
                    xferf[lrow * 260 + lcol] = acc[mf][nf][rg] + bias[mf][rg];
                }
            }
        __syncthreads();
        int n0b = chunk * 512 + u * 256;
#pragma unroll
        for (int i = 0; i < 16; ++i) {
            int row = (t >> 6) + 4 * i;
            int seg = t & 63;
            float4 v = *reinterpret_cast<const float4*>(&xferf[row * 260 + seg * 4]);
            *reinterpret_cast<float4*>(&outp[(size_t)(mt * 64 + row) * HW + n0b + seg * 4]) = v;
        }
        __syncthreads();
    }
}

extern "C" void kernel_launch(void* const* d_in, const int* in_sizes, int n_in,
                              void* d_out, int out_size, void* d_ws, size_t ws_size,
                              hipStream_t stream) {
    const float* x      = (const float*)d_in[0];
    const float* mask   = (const float*)d_in[1];
    const float* qkv_w  = (const float*)d_in[2];
    const float* qkv_b  = (const float*)d_in[3];
    const float* dw_w   = (const float*)d_in[4];
    const float* dw_b   = (const float*)d_in[5];
    const float* out_w  = (const float*)d_in[6];
    const float* out_b  = (const float*)d_in[7];
    const float* dtemp  = (const float*)d_in[8];
    const float* stemp  = (const float*)d_in[9];
    const float* tboost = (const float*)d_in[10];
    float* out = (float*)d_out;

    char* ws = (char*)d_ws;
    // layout (bytes):
    //   qkv bf16   : [0, 150994944)          per-batch regions: q[0,192) k[192,384) v[384,576)
    //                after k2a: K-> q-region, Vquad -> k-region
    //   X4/Qp bf16 : [150994944, 201326592)  (X4 dead after K1; Qp reuses it)
    //   gram       : [201326592, 201621504)
    //   ssq        : [201621504, 201627648)
    //   ssk        : [201627648, 201633792)
    //   W2         : [201634048, 202813696)
    ushort* qkv = (ushort*)(ws);
    ushort* XV  = (ushort*)(ws + 150994944);
    float* gram = (float*)(ws + 201326592);
    float* ssq  = (float*)(ws + 201621504);
    float* ssk  = (float*)(ws + 201627648);
    float* W2   = (float*)(ws + 201634048);

    hipMemsetAsync(ws + 201326592, 0, 294912 + 6144 + 6144, stream);
    k0_cvt<<<NB * 48 * HW / 256, 256, 0, stream>>>(x, XV);
    k1_qkv<<<1152, 256, 0, stream>>>(qkv_w, qkv_b, (const uint2*)XV, qkv);
    // q: src qkv part0 -> Qp (XV slot, contiguous 192ch/batch)
    k2a_dw<<<3072, 256, 0, stream>>>(qkv, (size_t)C3 * HW, XV, (size_t)NC * HW,
                                     dw_w, dw_b, 0, mask, tboost, 0);
    // k: src qkv part1 -> K into qkv q-region (per-batch stride C3*HW)
    k2a_dw<<<3072, 256, 0, stream>>>(qkv + (size_t)NC * HW, (size_t)C3 * HW,
                                     qkv, (size_t)C3 * HW,
                                     dw_w, dw_b, NC, mask, tboost, 0);
    // v: src qkv part2 -> quad-interleaved into qkv k-region
    k2a_dw<<<3072, 256, 0, stream>>>(qkv + (size_t)2 * NC * HW, (size_t)C3 * HW,
                                     qkv + (size_t)NC * HW, (size_t)C3 * HW,
                                     dw_w, dw_b, 2 * NC, mask, tboost, 1);
    k2b_gram<<<512, 256, 0, stream>>>(XV, qkv, (size_t)C3 * HW, gram, ssq, ssk);
    k4_w2<<<32, 256, 0, stream>>>(gram, ssq, ssk, mask, dtemp, stemp, out_w, W2);
    k5_out<<<768, 256, 0, stream>>>(W2, out_b, qkv + (size_t)NC * HW, (size_t)C3 * HW, out);
}

// Round 4
// 479.717 us; speedup vs baseline: 1.0412x; 1.0412x over previous
//
#include <hip/hip_runtime.h>
#include <hip/hip_bf16.h>

#define NB 8
#define NC 192
#define NH 4
#define CH 48
#define C3 576
#define HW 16384
#define IW 128

typedef __attribute__((ext_vector_type(4))) float f32x4;
typedef __attribute__((ext_vector_type(8))) short short8;

__device__ __forceinline__ unsigned short f2bf(float f) {
    union { float f; unsigned u; } v; v.f = f;
    unsigned u = v.u;
    return (unsigned short)((u + 0x7FFFu + ((u >> 16) & 1u)) >> 16);
}
__device__ __forceinline__ float bf2f(unsigned short h) {
    union { unsigned u; float f; } v; v.u = ((unsigned)h) << 16;
    return v.f;
}

// ---------------- K0: convert x (fp32 NCHW) -> X4 bf16 quad-interleaved [b][k/4][n][k%4]
__global__ __launch_bounds__(256) void k0_cvt(const float* __restrict__ x,
                                              ushort* __restrict__ X4) {
    unsigned i = blockIdx.x * 256u + threadIdx.x;   // quad id: (b*48+kq)*HW + n
    unsigned n = i & (HW - 1);
    unsigned bk = i >> 14;
    const float* xp = x + (size_t)bk * 4 * HW + n;
    ushort4 v;
    v.x = f2bf(xp[0]);
    v.y = f2bf(xp[HW]);
    v.z = f2bf(xp[2 * HW]);
    v.w = f2bf(xp[3 * HW]);
    *reinterpret_cast<ushort4*>(X4 + (size_t)i * 4) = v;
}

// ---------------- K1: qkv 1x1 conv as bf16 MFMA GEMM, coalesced epilogue via LDS.
// XCD-grouped swizzle: panel p=(b,chunk) pinned to XCD p%8; the 9 mt-sharers of a
// panel are consecutive on that XCD -> X-panel stays in the XCD's private L2.
__global__ __launch_bounds__(256) void k1_qkv(const float* __restrict__ Wq,
                                              const float* __restrict__ bq,
                                              const uint2* __restrict__ X4,
                                              ushort* __restrict__ qkv) {
    __shared__ __align__(16) ushort xfer[64 * 264];   // stride 264: 16B-aligned rows, ~2-way banks
    int bid = blockIdx.x;
    int xcd = bid & 7;
    int seq = bid >> 3;
    int mt = seq % 9;
    int pg = seq / 9;
    int p = pg * 8 + xcd;
    int chunk = p & 15;
    int b = p >> 4;
    int t = threadIdx.x;
    int lane = t & 63, w = t >> 6;
    int g = lane >> 4, r = lane & 15;
    int mw = w & 1, nw = w >> 1;
    int mbase = mt * 64 + mw * 32;

    short8 a[2][6];
#pragma unroll
    for (int mf = 0; mf < 2; ++mf)
#pragma unroll
        for (int ks = 0; ks < 6; ++ks) {
            const float* wp = Wq + (mbase + mf * 16 + r) * NC + ks * 32 + 8 * g;
            short8 av;
#pragma unroll
            for (int j = 0; j < 8; ++j) av[j] = (short)f2bf(wp[j]);
            a[mf][ks] = av;
        }
    float bias[2][4];
#pragma unroll
    for (int mf = 0; mf < 2; ++mf)
#pragma unroll
        for (int rg = 0; rg < 4; ++rg)
            bias[mf][rg] = bq[mbase + mf * 16 + 4 * g + rg];

    const uint2* Xb = X4 + (size_t)b * 48 * HW;
    ushort* outb = qkv + (size_t)b * C3 * HW;

    for (int u = 0; u < 4; ++u) {
        int n0 = chunk * 1024 + u * 256 + nw * 128;
        f32x4 acc[2][8];
#pragma unroll
        for (int mf = 0; mf < 2; ++mf)
#pragma unroll
            for (int nf = 0; nf < 8; ++nf) acc[mf][nf] = (f32x4){0.f, 0.f, 0.f, 0.f};
#pragma unroll
        for (int ks = 0; ks < 6; ++ks) {
            short8 bb[8];
#pragma unroll
            for (int nf = 0; nf < 8; ++nf) {
                int n = n0 + nf * 16 + r;
                int kq = 8 * ks + 2 * g;
                union { uint2 u2[2]; short8 s; } uu;
                uu.u2[0] = Xb[(size_t)kq * HW + n];
                uu.u2[1] = Xb[(size_t)(kq + 1) * HW + n];
                bb[nf] = uu.s;
            }
#pragma unroll
            for (int mf = 0; mf < 2; ++mf)
#pragma unroll
                for (int nf = 0; nf < 8; ++nf)
                    acc[mf][nf] = __builtin_amdgcn_mfma_f32_16x16x32_bf16(
                        a[mf][ks], bb[nf], acc[mf][nf], 0, 0, 0);
        }
        // epilogue: fragments -> LDS tile -> coalesced short8 stores
#pragma unroll
        for (int mf = 0; mf < 2; ++mf)
#pragma unroll
            for (int nf = 0; nf < 8; ++nf) {
                int lcol = nw * 128 + nf * 16 + r;
#pragma unroll
                for (int rg = 0; rg < 4; ++rg) {
                    int lrow = mw * 32 + mf * 16 + 4 * g + rg;
                    xfer[lrow * 264 + lcol] = f2bf(acc[mf][nf][rg] + bias[mf][rg]);
                }
            }
        __syncthreads();
        int n0b = chunk * 1024 + u * 256;
#pragma unroll
        for (int i = 0; i < 8; ++i) {
            int row = (t >> 5) + 8 * i;
            int seg = t & 31;
            short8 v = *reinterpret_cast<const short8*>(&xfer[row * 264 + seg * 8]);
            *reinterpret_cast<short8*>(&outb[(size_t)(mt * 64 + row) * HW + n0b + seg * 8]) = v;
        }
        __syncthreads();
    }
}

// ---------------- K2a: streaming depthwise 3x3 over 4 channels x (128x16) strip.
// mode 0: write plain [b][ch][n] bf16 to dst (batch stride dbs)
// mode 1: scale by (1+mask*tb), write quad-interleaved [b][ch/4][n][ch%4]
__global__ __launch_bounds__(256) void k2a_dw(const ushort* __restrict__ src,
                                              size_t sbs,
                                              ushort* __restrict__ dst,
                                              size_t dbs,
                                              const float* __restrict__ dw_w,
                                              const float* __restrict__ dw_b,
                                              int wb_off,
                                              const float* __restrict__ mask,
                                              const float* __restrict__ tboost,
                                              int mode) {
    __shared__ ushort stage[4][18][128];
    int bid = blockIdx.x;
    int b = bid / 384;
    int rem = bid - b * 384;
    int grp = rem >> 3;         // 0..47 (4-channel group)
    int strip = rem & 7;        // 0..7 (16-row strip)
    int t = threadIdx.x;
    int y = t >> 4;             // 0..15
    int x0 = (t & 15) * 8;

    // stage: 4 ch x 18 rows x 16 short8-segments, coalesced
    for (int u = t; u < 1152; u += 256) {
        int ci = u / 288;
        int r2 = u - ci * 288;
        int row = r2 >> 4;
        int seg = r2 & 15;
        int gy = strip * 16 - 1 + row;
        short8 v = (short8){0, 0, 0, 0, 0, 0, 0, 0};
        if ((unsigned)gy < 128u)
            v = *reinterpret_cast<const short8*>(
                src + (size_t)b * sbs + (size_t)(grp * 4 + ci) * HW + gy * IW + seg * 8);
        *reinterpret_cast<short8*>(&stage[ci][row][seg * 8]) = v;
    }
    __syncthreads();

    float o4[4][8];
#pragma unroll
    for (int ci = 0; ci < 4; ++ci) {
        int gch = wb_off + grp * 4 + ci;
        const float* wt = dw_w + gch * 9;
        float w0 = wt[0], w1 = wt[1], w2 = wt[2];
        float w3 = wt[3], w4 = wt[4], w5 = wt[5];
        float w6 = wt[6], w7 = wt[7], w8 = wt[8];
        float bsv = dw_b[gch];
        float o[8];
#pragma unroll
        for (int p = 0; p < 8; ++p) o[p] = bsv;
#pragma unroll
        for (int dy = 0; dy < 3; ++dy) {
            int row = y + dy;
            short8 m = *reinterpret_cast<const short8*>(&stage[ci][row][x0]);
            float v[10];
            v[0] = (x0 > 0) ? bf2f(stage[ci][row][x0 - 1]) : 0.f;
            v[9] = (x0 < 120) ? bf2f(stage[ci][row][x0 + 8]) : 0.f;
#pragma unroll
            for (int j = 0; j < 8; ++j) v[j + 1] = bf2f((unsigned short)m[j]);
            float wa = (dy == 0) ? w0 : (dy == 1) ? w3 : w6;
            float wb = (dy == 0) ? w1 : (dy == 1) ? w4 : w7;
            float wc = (dy == 0) ? w2 : (dy == 1) ? w5 : w8;
#pragma unroll
            for (int p = 0; p < 8; ++p)
                o[p] += v[p] * wa + v[p + 1] * wb + v[p + 2] * wc;
        }
#pragma unroll
        for (int p = 0; p < 8; ++p) o4[ci][p] = o[p];
    }

    int n = (strip * 16 + y) * IW + x0;
    if (mode == 0) {
#pragma unroll
        for (int ci = 0; ci < 4; ++ci) {
            short8 pk;
#pragma unroll
            for (int p = 0; p < 8; ++p) pk[p] = (short)f2bf(o4[ci][p]);
            *reinterpret_cast<short8*>(
                dst + (size_t)b * dbs + (size_t)(grp * 4 + ci) * HW + n) = pk;
        }
    } else {
        float tb = tboost[0];
        tb = fminf(fmaxf(tb, 0.1f), 0.5f);
        const float* mp = mask + (size_t)b * HW + n;
        float vs[8];
#pragma unroll
        for (int p = 0; p < 8; ++p) vs[p] = 1.f + mp[p] * tb;
        ushort* dp = dst + (size_t)b * dbs + ((size_t)grp * HW + n) * 4;
#pragma unroll
        for (int p = 0; p < 8; p += 2) {
            uint4 W;
            unsigned a0 = f2bf(o4[0][p] * vs[p]), a1 = f2bf(o4[1][p] * vs[p]);
            unsigned a2 = f2bf(o4[2][p] * vs[p]), a3 = f2bf(o4[3][p] * vs[p]);
            unsigned b0 = f2bf(o4[0][p + 1] * vs[p + 1]), b1 = f2bf(o4[1][p + 1] * vs[p + 1]);
            unsigned b2 = f2bf(o4[2][p + 1] * vs[p + 1]), b3 = f2bf(o4[3][p + 1] * vs[p + 1]);
            W.x = a0 | (a1 << 16);
            W.y = a2 | (a3 << 16);
            W.z = b0 | (b1 << 16);
            W.w = b2 | (b3 << 16);
            *reinterpret_cast<uint4*>(dp + p * 4) = W;
        }
    }
}

// ---------------- K2b: Gram + sumsq via MFMA. grid = b(8)*h(4)*chunk(16), chunk=1024 n.
__global__ __launch_bounds__(256) void k2b_gram(const ushort* __restrict__ Qp,
                                                const ushort* __restrict__ Kp,
                                                size_t kbs,
                                                float* __restrict__ gram,
                                                float* __restrict__ ssq,
                                                float* __restrict__ ssk) {
    int bid = blockIdx.x;
    int chunk = bid & 15;
    int h = (bid >> 4) & 3;
    int b = bid >> 6;
    int t = threadIdx.x;
    int lane = t & 63, wv = t >> 6;
    int g = lane >> 4, r = lane & 15;

    const ushort* qb = Qp + (size_t)b * NC * HW + (size_t)(h * CH) * HW;
    const ushort* kb = Kp + (size_t)b * kbs + (size_t)(h * CH) * HW;

    f32x4 gacc[3][3], gqq[3], gkk[3];
#pragma unroll
    for (int i = 0; i < 3; ++i) {
        gqq[i] = (f32x4){0.f, 0.f, 0.f, 0.f};
        gkk[i] = (f32x4){0.f, 0.f, 0.f, 0.f};
#pragma unroll
        for (int j = 0; j < 3; ++j) gacc[i][j] = (f32x4){0.f, 0.f, 0.f, 0.f};
    }

    int nbase = chunk * 1024 + wv * 256;
#pragma unroll 2
    for (int ks = 0; ks < 8; ++ks) {
        int p0 = nbase + ks * 32 + 8 * g;
        short8 qa[3], ka[3];
#pragma unroll
        for (int f = 0; f < 3; ++f) {
            qa[f] = *reinterpret_cast<const short8*>(qb + (size_t)(f * 16 + r) * HW + p0);
            ka[f] = *reinterpret_cast<const short8*>(kb + (size_t)(f * 16 + r) * HW + p0);
        }
#pragma unroll
        for (int cf = 0; cf < 3; ++cf)
#pragma unroll
            for (int df = 0; df < 3; ++df)
                gacc[cf][df] = __builtin_amdgcn_mfma_f32_16x16x32_bf16(
                    qa[cf], ka[df], gacc[cf][df], 0, 0, 0);
#pragma unroll
        for (int f = 0; f < 3; ++f) {
            gqq[f] = __builtin_amdgcn_mfma_f32_16x16x32_bf16(qa[f], qa[f], gqq[f], 0, 0, 0);
            gkk[f] = __builtin_amdgcn_mfma_f32_16x16x32_bf16(ka[f], ka[f], gkk[f], 0, 0, 0);
        }
    }

    float* gr = gram + (size_t)(b * NH + h) * 2304;
#pragma unroll
    for (int cf = 0; cf < 3; ++cf)
#pragma unroll
        for (int df = 0; df < 3; ++df)
#pragma unroll
            for (int rg = 0; rg < 4; ++rg)
                atomicAdd(gr + (cf * 16 + 4 * g + rg) * 48 + df * 16 + r,
                          gacc[cf][df][rg]);
    // diagonal of qq/kk blocks: D[row=4g+rg][col=r]; diag where r==4g+rg
    if ((r >> 2) == g) {
        int rg = r & 3;
#pragma unroll
        for (int f = 0; f < 3; ++f) {
            atomicAdd(ssq + (b * NH + h) * CH + f * 16 + r, gqq[f][rg]);
            atomicAdd(ssk + (b * NH + h) * CH + f * 16 + r, gkk[f][rg]);
        }
    }
}

// ---------------- K4: texture mean + normalize Gram + softmax + W2 = out_w * blockdiag(attn)
__global__ __launch_bounds__(256) void k4_w2(const float* __restrict__ gram,
                                             const float* __restrict__ ssq,
                                             const float* __restrict__ ssk,
                                             const float* __restrict__ mask,
                                             const float* __restrict__ dtemp,
                                             const float* __restrict__ stemp,
                                             const float* __restrict__ out_w,
                                             float* __restrict__ W2) {
    __shared__ float att[48][48];
    __shared__ float invk_s[48];
    __shared__ float red[4];
    __shared__ float tl_s;
    int bid = blockIdx.x;
    int h = bid & 3, b = bid >> 2;
    int t = threadIdx.x;
    // texture level = mean(mask[b]) (redundant across the 4 h-blocks; tiny, L2-hot)
    {
        float s = 0.f;
        const float* mp = mask + (size_t)b * HW;
        for (int i = t; i < HW; i += 256) s += mp[i];
#pragma unroll
        for (int off = 32; off > 0; off >>= 1) s += __shfl_xor(s, off);
        if ((t & 63) == 0) red[t >> 6] = s;
        __syncthreads();
        if (t == 0) tl_s = (red[0] + red[1] + red[2] + red[3]) * (1.f / HW);
        __syncthreads();
    }
    float tl = tl_s;
    float temp = dtemp[h] * tl + stemp[h] * (1.f - tl);
    const float* G = gram + (size_t)(b * NH + h) * 2304;
    const float* sq = ssq + (b * NH + h) * CH;
    const float* sk = ssk + (b * NH + h) * CH;
    if (t < 48) invk_s[t] = 1.f / fmaxf(sqrtf(sk[t]), 1e-12f);
    __syncthreads();
    if (t < 48) {
        float invq = temp / fmaxf(sqrtf(sq[t]), 1e-12f);
        float mx = -1e30f;
        for (int d = 0; d < 48; ++d) {
            float v = G[t * 48 + d] * invq * invk_s[d];
            att[t][d] = v;
            mx = fmaxf(mx, v);
        }
        float sum = 0.f;
        for (int d = 0; d < 48; ++d) {
            float e = __expf(att[t][d] - mx);
            att[t][d] = e;
            sum += e;
        }
        float inv = 1.f / sum;
        for (int d = 0; d < 48; ++d) att[t][d] *= inv;
    }
    __syncthreads();
    for (int i = t; i < NC * 48; i += 256) {
        int oc = i / 48, d = i - oc * 48;
        float s = 0.f;
        for (int c = 0; c < 48; ++c) s += out_w[oc * NC + h * CH + c] * att[c][d];
        W2[(size_t)(b * NC + oc) * NC + h * CH + d] = s;
    }
}

// ---------------- K5: out[b][m][n] = sum_j W2[b][m][j] * v_scaled[b][j][n] + out_b[m]
// XCD-grouped swizzle like k1: panel p=(b,chunk) -> XCD p%8, 3 mt-sharers adjacent.
__global__ __launch_bounds__(256) void k5_out(const float* __restrict__ W2,
                                              const float* __restrict__ ob,
                                              const ushort* __restrict__ Vt4base,
                                              size_t vbs,
                                              float* __restrict__ out) {
    __shared__ __align__(16) float xferf[64 * 260];   // stride 260 f32: 16B-aligned, 2-way banks
    int bid = blockIdx.x;
    int xcd = bid & 7;
    int seq = bid >> 3;
    int mt = seq % 3;
    int pg = seq / 3;
    int p = pg * 8 + xcd;
    int chunk = p & 31;
    int b = p >> 5;
    int t = threadIdx.x;
    int lane = t & 63, w = t >> 6;
    int g = lane >> 4, r = lane & 15;
    int mw = w & 1, nw = w >> 1;
    int mbase = mt * 64 + mw * 32;
    const float* Wb = W2 + (size_t)b * NC * NC;

    short8 a[2][6];
#pragma unroll
    for (int mf = 0; mf < 2; ++mf)
#pragma unroll
        for (int ks = 0; ks < 6; ++ks) {
            const float* wp = Wb + (mbase + mf * 16 + r) * NC + ks * 32 + 8 * g;
            short8 av;
#pragma unroll
            for (int j = 0; j < 8; ++j) av[j] = (short)f2bf(wp[j]);
            a[mf][ks] = av;
        }
    float bias[2][4];
#pragma unroll
    for (int mf = 0; mf < 2; ++mf)
#pragma unroll
        for (int rg = 0; rg < 4; ++rg)
            bias[mf][rg] = ob[mbase + mf * 16 + 4 * g + rg];

    const uint2* Vb = reinterpret_cast<const uint2*>(Vt4base + (size_t)b * vbs);
    float* outp = out + (size_t)b * NC * HW;

    for (int u = 0; u < 2; ++u) {
        int n0 = chunk * 512 + u * 256 + nw * 128;
        f32x4 acc[2][8];
#pragma unroll
        for (int mf = 0; mf < 2; ++mf)
#pragma unroll
            for (int nf = 0; nf < 8; ++nf) acc[mf][nf] = (f32x4){0.f, 0.f, 0.f, 0.f};
#pragma unroll
        for (int ks = 0; ks < 6; ++ks) {
            short8 bb[8];
#pragma unroll
            for (int nf = 0; nf < 8; ++nf) {
                int n = n0 + nf * 16 + r;
                int kq = 8 * ks + 2 * g;
                union { uint2 u2[2]; short8 s; } uu;
                uu.u2[0] = Vb[(size_t)kq * HW + n];
                uu.u2[1] = Vb[(size_t)(kq + 1) * HW + n];
                bb[nf] = uu.s;
            }
#pragma unroll
            for (int mf = 0; mf < 2; ++mf)
#pragma unroll
                for (int nf = 0; nf < 8; ++nf)
                    acc[mf][nf] = __builtin_amdgcn_mfma_f32_16x16x32_bf16(
                        a[mf][ks], bb[nf], acc[mf][nf], 0, 0, 0);
        }
        // epilogue: fragments -> LDS -> coalesced float4 stores
#pragma unroll
        for (int mf = 0; mf < 2; ++mf)
#pragma unroll
            for (int nf = 0; nf < 8; ++nf) {
                int lcol = nw * 128 + nf * 16 + r;
#pragma unroll
                for (int rg = 0; rg < 4; ++rg) {
                    int lrow = mw * 32 + mf * 16 + 4 * g + rg;
                    xferf[lrow * 260 + lcol] = acc[mf][nf][rg] + bias[mf][rg];
                }
            }
        __syncthreads();
        int n0b = chunk * 512 + u * 256;
#pragma unroll
        for (int i = 0; i < 16; ++i) {
            int row = (t >> 6) + 4 * i;
            int seg = t & 63;
            float4 v = *reinterpret_cast<const float4*>(&xferf[row * 260 + seg * 4]);
            *reinterpret_cast<float4*>(&outp[(size_t)(mt * 64 + row) * HW + n0b + seg * 4]) = v;
        }
        __syncthreads();
    }
}

extern "C" void kernel_launch(void* const* d_in, const int* in_sizes, int n_in,
                              void* d_out, int out_size, void* d_ws, size_t ws_size,
                              hipStream_t stream) {
    const float* x      = (const float*)d_in[0];
    const float* mask   = (const float*)d_in[1];
    const float* qkv_w  = (const float*)d_in[2];
    const float* qkv_b  = (const float*)d_in[3];
    const float* dw_w   = (const float*)d_in[4];
    const float* dw_b   = (const float*)d_in[5];
    const float* out_w  = (const float*)d_in[6];
    const float* out_b  = (const float*)d_in[7];
    const float* dtemp  = (const float*)d_in[8];
    const float* stemp  = (const float*)d_in[9];
    const float* tboost = (const float*)d_in[10];
    float* out = (float*)d_out;

    char* ws = (char*)d_ws;
    // layout (bytes):
    //   qkv bf16   : [0, 150994944)          per-batch regions: q[0,192) k[192,384) v[384,576)
    //                after k2a: K-> q-region, Vquad -> k-region
    //   X4/Qp bf16 : [150994944, 201326592)  (X4 dead after K1; Qp reuses it)
    //   gram       : [201326592, 201621504)
    //   ssq        : [201621504, 201627648)
    //   ssk        : [201627648, 201633792)
    //   W2         : [201634048, 202813696)
    ushort* qkv = (ushort*)(ws);
    ushort* XV  = (ushort*)(ws + 150994944);
    float* gram = (float*)(ws + 201326592);
    float* ssq  = (float*)(ws + 201621504);
    float* ssk  = (float*)(ws + 201627648);
    float* W2   = (float*)(ws + 201634048);

    hipMemsetAsync(ws + 201326592, 0, 294912 + 6144 + 6144, stream);
    k0_cvt<<<NB * 48 * HW / 256, 256, 0, stream>>>(x, XV);
    k1_qkv<<<1152, 256, 0, stream>>>(qkv_w, qkv_b, (const uint2*)XV, qkv);
    // q: src qkv part0 -> Qp (XV slot, contiguous 192ch/batch)
    k2a_dw<<<3072, 256, 0, stream>>>(qkv, (size_t)C3 * HW, XV, (size_t)NC * HW,
                                     dw_w, dw_b, 0, mask, tboost, 0);
    // k: src qkv part1 -> K into qkv q-region (per-batch stride C3*HW)
    k2a_dw<<<3072, 256, 0, stream>>>(qkv + (size_t)NC * HW, (size_t)C3 * HW,
                                     qkv, (size_t)C3 * HW,
                                     dw_w, dw_b, NC, mask, tboost, 0);
    // v: src qkv part2 -> quad-interleaved into qkv k-region
    k2a_dw<<<3072, 256, 0, stream>>>(qkv + (size_t)2 * NC * HW, (size_t)C3 * HW,
                                     qkv + (size_t)NC * HW, (size_t)C3 * HW,
                                     dw_w, dw_b, 2 * NC, mask, tboost, 1);
    k2b_gram<<<512, 256, 0, stream>>>(XV, qkv, (size_t)C3 * HW, gram, ssq, ssk);
    k4_w2<<<32, 256, 0, stream>>>(gram, ssq, ssk, mask, dtemp, stemp, out_w, W2);
    k5_out<<<768, 256, 0, stream>>>(W2, out_b, qkv + (size_t)NC * HW, (size_t)C3 * HW, out);
}